// Round 1
// baseline (5754.144 us; speedup 1.0000x reference)
//
#include <hip/hip_runtime.h>
#include <hip/hip_bf16.h>

#define SEQ 128
#define BATCH 64
#define EMB 512
#define HID 1024
#define VOCAB 10000
#define NPAD 10240
#define MROWS 8192  // SEQ*BATCH
#define BH (BATCH * HID)

typedef unsigned short u16;
typedef unsigned int u32;
typedef __attribute__((ext_vector_type(4))) float f32x4;
typedef __attribute__((ext_vector_type(8))) short short8;
typedef __attribute__((ext_vector_type(8))) __bf16 bf16x8;

__device__ __forceinline__ u16 f2bf(float f) {
  u32 u = __builtin_bit_cast(u32, f);
  u = (u + 0x7fffu + ((u >> 16) & 1u)) >> 16;  // RNE
  return (u16)u;
}
__device__ __forceinline__ float bf2f(u16 h) {
  u32 u = ((u32)h) << 16;
  return __builtin_bit_cast(float, u);
}
__device__ __forceinline__ f32x4 mfma_bf16(short8 a, short8 b, f32x4 c) {
  return __builtin_amdgcn_mfma_f32_16x16x32_bf16(
      __builtin_bit_cast(bf16x8, a), __builtin_bit_cast(bf16x8, b), c, 0, 0, 0);
}
__device__ __forceinline__ void gload16(const u16* g, u16* l) {
  __builtin_amdgcn_global_load_lds(
      (__attribute__((address_space(1))) void*)g,
      (__attribute__((address_space(3))) void*)l, 16, 0, 0);
}

// ---------------- prep kernels ----------------
__global__ void k_cvt(const float* __restrict__ s, u16* __restrict__ d, int n) {
  int i = blockIdx.x * 256 + threadIdx.x;
  if (i < n) d[i] = f2bf(s[i]);
}
__global__ void k_cvt_wout(const float* __restrict__ s, u16* __restrict__ d) {
  int i = blockIdx.x * 256 + threadIdx.x;  // over NPAD*HID
  if (i < NPAD * HID) {
    int row = i >> 10;
    d[i] = (row < VOCAB) ? f2bf(s[i]) : (u16)0;
  }
}
__global__ void k_gather(const int* __restrict__ toks, const float* __restrict__ emb,
                         u16* __restrict__ X) {
  int i = blockIdx.x * 256 + threadIdx.x;  // over MROWS*EMB
  if (i < MROWS * EMB) {
    int r = i >> 9, e = i & 511;
    X[i] = f2bf(emb[(size_t)toks[r] * EMB + e]);
  }
}

// ---------------- big GEMM: C[M,N] = A[M,K] @ B[N,K]^T (+bias) ----------------
// 128x128 tile, BK=32, 4 waves (2x2), each wave 64x64 via 4x4 mfma_16x16x32 frags.
__global__ __launch_bounds__(256) void k_gemm(const u16* __restrict__ A, const u16* __restrict__ B,
                                              float* __restrict__ C, int K, int ldc, int nvalid,
                                              const float* __restrict__ bias) {
  __shared__ u16 As[128 * 32];
  __shared__ u16 Bs[128 * 32];
  const int tid = threadIdx.x, lane = tid & 63, wid = tid >> 6;
  const int wm = wid >> 1, wn = wid & 1;
  const int bm = blockIdx.x, bn = blockIdx.y;
  const int r4 = tid >> 2, c8 = (tid & 3) * 8;
  f32x4 acc[4][4] = {};
  const u16* Ab = A + (size_t)bm * 128 * K;
  const u16* Bb = B + (size_t)bn * 128 * K;
  const int nkt = K >> 5;
  for (int kt = 0; kt < nkt; ++kt) {
    const int k0 = kt * 32;
    __syncthreads();  // protect LDS from overwrite
#pragma unroll
    for (int c = 0; c < 2; ++c) {
      gload16(Ab + (size_t)(c * 64 + r4) * K + k0 + c8, &As[c * 2048 + wid * 512]);
      gload16(Bb + (size_t)(c * 64 + r4) * K + k0 + c8, &Bs[c * 2048 + wid * 512]);
    }
    __syncthreads();  // drains vmcnt: LDS tiles ready
    short8 af[4], bf[4];
    const int rr = lane & 15, kq = (lane >> 4) * 8;
#pragma unroll
    for (int mi = 0; mi < 4; ++mi) af[mi] = *(const short8*)&As[(wm * 64 + mi * 16 + rr) * 32 + kq];
#pragma unroll
    for (int ni = 0; ni < 4; ++ni) bf[ni] = *(const short8*)&Bs[(wn * 64 + ni * 16 + rr) * 32 + kq];
#pragma unroll
    for (int mi = 0; mi < 4; ++mi)
#pragma unroll
      for (int ni = 0; ni < 4; ++ni) acc[mi][ni] = mfma_bf16(af[mi], bf[ni], acc[mi][ni]);
  }
#pragma unroll
  for (int mi = 0; mi < 4; ++mi)
#pragma unroll
    for (int ni = 0; ni < 4; ++ni) {
      const int col = bn * 128 + wn * 64 + ni * 16 + (lane & 15);
      if (col < nvalid) {
        const float bb = bias ? bias[col] : 0.0f;
#pragma unroll
        for (int r = 0; r < 4; ++r) {
          const int row = bm * 128 + wm * 64 + mi * 16 + (lane >> 4) * 4 + r;
          C[(size_t)row * ldc + col] = acc[mi][ni][r] + bb;
        }
      }
    }
}

// ---------------- recurrent step ----------------
// One 64x64-column slab of a (64 x 1024) @ (1024 x 1024)^T product per block/job.
__device__ __forceinline__ void slab_gemm(const u16* __restrict__ A, const u16* __restrict__ B,
                                          int nb, int wid, int lane, f32x4 acc[4]) {
  const int rr = lane & 15, kq = (lane >> 4) * 8;
  const u16* ap = A + (size_t)(wid * 16 + rr) * HID + kq;
  const u16* bp = B + (size_t)(nb * 64 + rr) * HID + kq;
#pragma unroll 4
  for (int kt = 0; kt < HID / 32; ++kt) {
    short8 af = *(const short8*)(ap + kt * 32);
#pragma unroll
    for (int j = 0; j < 4; ++j) {
      short8 bf = *(const short8*)(bp + (size_t)j * 16 * HID + kt * 32);
      acc[j] = mfma_bf16(af, bf, acc[j]);
    }
  }
}

// Launch t=-1 (bootstrap: h0[0] only), then t=0..127.
// job0 (blocks 0..15):  H1[t]   = tanh(H0[t]@W1x^T + H1[t-1]@W1h^T + b1)
// job1 (blocks 16..31): H0[t+1] = tanh(H0[t]@W0h^T + pre0[t+1] + b0)
__global__ __launch_bounds__(256) void k_step(int t, const u16* __restrict__ W0h,
                                              const u16* __restrict__ W1x,
                                              const u16* __restrict__ W1h,
                                              const float* __restrict__ pre0,
                                              const float* __restrict__ b0,
                                              const float* __restrict__ b1, u16* __restrict__ H0all,
                                              u16* __restrict__ H1all, const u16* __restrict__ Zb) {
  const int job = blockIdx.x >> 4, nb = blockIdx.x & 15;
  const int lane = threadIdx.x & 63, wid = threadIdx.x >> 6;
  f32x4 acc[4] = {};
  if (job == 0) {
    if (t < 0) return;
    const u16* A1 = H0all + (size_t)t * BH;
    slab_gemm(A1, W1x, nb, wid, lane, acc);
    const u16* A2 = (t == 0) ? (Zb + BH) : (H1all + (size_t)(t - 1) * BH);
    slab_gemm(A2, W1h, nb, wid, lane, acc);
    u16* out = H1all + (size_t)t * BH;
#pragma unroll
    for (int j = 0; j < 4; ++j) {
      const int col = nb * 64 + j * 16 + (lane & 15);
      const float bb = b1[col];
#pragma unroll
      for (int r = 0; r < 4; ++r) {
        const int row = wid * 16 + (lane >> 4) * 4 + r;
        out[row * HID + col] = f2bf(tanhf(acc[j][r] + bb));
      }
    }
  } else {
    if (t == SEQ - 1) return;  // no h0[128] needed
    const u16* A1 = (t < 0) ? Zb : (H0all + (size_t)t * BH);
    slab_gemm(A1, W0h, nb, wid, lane, acc);
    const float* ci = pre0 + (size_t)(t + 1) * BH;
    u16* out = H0all + (size_t)(t + 1) * BH;
#pragma unroll
    for (int j = 0; j < 4; ++j) {
      const int col = nb * 64 + j * 16 + (lane & 15);
      const float bb = b0[col];
#pragma unroll
      for (int r = 0; r < 4; ++r) {
        const int row = wid * 16 + (lane >> 4) * 4 + r;
        out[row * HID + col] = f2bf(tanhf(acc[j][r] + ci[row * HID + col] + bb));
      }
    }
  }
}

__global__ void k_finalh(const u16* __restrict__ H0all, const u16* __restrict__ H1all,
                         float* __restrict__ out) {
  int i = blockIdx.x * 256 + threadIdx.x;
  if (i < 2 * BH) {
    u16 v = (i < BH) ? H0all[(size_t)(SEQ - 1) * BH + i] : H1all[(size_t)(SEQ - 1) * BH + (i - BH)];
    out[(size_t)MROWS * VOCAB + i] = bf2f(v);
  }
}

extern "C" void kernel_launch(void* const* d_in, const int* in_sizes, int n_in, void* d_out,
                              int out_size, void* d_ws, size_t ws_size, hipStream_t stream) {
  (void)in_sizes; (void)n_in; (void)out_size; (void)ws_size;
  const int* toks = (const int*)d_in[0];
  const float* hid0 = (const float*)d_in[1];
  const float* emb = (const float*)d_in[2];
  const float* W0x = (const float*)d_in[3];
  const float* W0h = (const float*)d_in[4];
  const float* b0 = (const float*)d_in[5];
  const float* W1x = (const float*)d_in[6];
  const float* W1h = (const float*)d_in[7];
  const float* b1 = (const float*)d_in[8];
  const float* Wout = (const float*)d_in[9];
  const float* bout = (const float*)d_in[10];
  float* out = (float*)d_out;

  char* ws = (char*)d_ws;
  u16* Xb = (u16*)(ws);                    //  8,388,608 B
  u16* W0xb = (u16*)(ws + 8388608);        //  1,048,576
  u16* W0hb = (u16*)(ws + 9437184);        //  2,097,152
  u16* W1xb = (u16*)(ws + 11534336);       //  2,097,152
  u16* W1hb = (u16*)(ws + 13631488);       //  2,097,152
  u16* Woutb = (u16*)(ws + 15728640);      // 20,971,520
  float* pre0 = (float*)(ws + 36700160);   // 33,554,432
  u16* H0all = (u16*)(ws + 70254592);      // 16,777,216
  u16* H1all = (u16*)(ws + 87031808);      // 16,777,216
  u16* Zb = (u16*)(ws + 103809024);        //    262,144  (total ~99.3 MB)

  auto g = [](int n) { return dim3((unsigned)((n + 255) / 256)); };
  k_cvt<<<g(HID * EMB), 256, 0, stream>>>(W0x, W0xb, HID * EMB);
  k_cvt<<<g(HID * HID), 256, 0, stream>>>(W0h, W0hb, HID * HID);
  k_cvt<<<g(HID * HID), 256, 0, stream>>>(W1x, W1xb, HID * HID);
  k_cvt<<<g(HID * HID), 256, 0, stream>>>(W1h, W1hb, HID * HID);
  k_cvt<<<g(2 * BH), 256, 0, stream>>>(hid0, Zb, 2 * BH);
  k_cvt_wout<<<g(NPAD * HID), 256, 0, stream>>>(Wout, Woutb);
  k_gather<<<g(MROWS * EMB), 256, 0, stream>>>(toks, emb, Xb);

  // pre0[all t] = X @ W0x^T   (8192 x 1024, K=512)
  k_gemm<<<dim3(MROWS / 128, HID / 128), 256, 0, stream>>>(Xb, W0xb, pre0, EMB, HID, HID, nullptr);

  // recurrence: bootstrap + 128 steps
  for (int t = -1; t < SEQ; ++t)
    k_step<<<dim3(32), 256, 0, stream>>>(t, W0hb, W1xb, W1hb, pre0, b0, b1, H0all, H1all, Zb);

  // logits = H1 @ Wout^T + bout   (8192 x 10240(pad), K=1024)
  k_gemm<<<dim3(MROWS / 128, NPAD / 128), 256, 0, stream>>>(H1all, Woutb, out, HID, VOCAB, VOCAB,
                                                            bout);
  k_finalh<<<g(2 * BH), 256, 0, stream>>>(H0all, H1all, out);
}

// Round 2
// 3727.147 us; speedup vs baseline: 1.5438x; 1.5438x over previous
//
#include <hip/hip_runtime.h>
#include <hip/hip_bf16.h>
#include <hip/hip_cooperative_groups.h>

namespace cg = cooperative_groups;

#define SEQ 128
#define BATCH 64
#define EMB 512
#define HID 1024
#define VOCAB 10000
#define NPAD 10240
#define MROWS 8192  // SEQ*BATCH
#define BH (BATCH * HID)

typedef unsigned short u16;
typedef unsigned int u32;
typedef __attribute__((ext_vector_type(4))) float f32x4;
typedef __attribute__((ext_vector_type(8))) short short8;
typedef __attribute__((ext_vector_type(8))) __bf16 bf16x8;

__device__ __forceinline__ u16 f2bf(float f) {
  u32 u = __builtin_bit_cast(u32, f);
  u = (u + 0x7fffu + ((u >> 16) & 1u)) >> 16;  // RNE
  return (u16)u;
}
__device__ __forceinline__ float bf2f(u16 h) {
  u32 u = ((u32)h) << 16;
  return __builtin_bit_cast(float, u);
}
__device__ __forceinline__ f32x4 mfma_bf16(short8 a, short8 b, f32x4 c) {
  return __builtin_amdgcn_mfma_f32_16x16x32_bf16(
      __builtin_bit_cast(bf16x8, a), __builtin_bit_cast(bf16x8, b), c, 0, 0, 0);
}
__device__ __forceinline__ void gload16(const u16* g, u16* l) {
  __builtin_amdgcn_global_load_lds(
      (__attribute__((address_space(1))) void*)g,
      (__attribute__((address_space(3))) void*)l, 16, 0, 0);
}

// ---------------- prep kernels ----------------
__global__ void k_cvt(const float* __restrict__ s, u16* __restrict__ d, int n) {
  int i = blockIdx.x * 256 + threadIdx.x;
  if (i < n) d[i] = f2bf(s[i]);
}
__global__ void k_cvt_wout(const float* __restrict__ s, u16* __restrict__ d) {
  int i = blockIdx.x * 256 + threadIdx.x;  // over NPAD*HID
  if (i < NPAD * HID) {
    int row = i >> 10;
    d[i] = (row < VOCAB) ? f2bf(s[i]) : (u16)0;
  }
}
__global__ void k_gather(const int* __restrict__ toks, const float* __restrict__ emb,
                         u16* __restrict__ X) {
  int i = blockIdx.x * 256 + threadIdx.x;  // over MROWS*EMB
  if (i < MROWS * EMB) {
    int r = i >> 9, e = i & 511;
    X[i] = f2bf(emb[(size_t)toks[r] * EMB + e]);
  }
}

// ---------------- big GEMM: C[M,N] = A[M,K] @ B[N,K]^T (+bias) ----------------
// 128x128 tile, BK=32, 4 waves (2x2), each wave 64x64 via 4x4 mfma_16x16x32 frags.
// LDS tiles XOR-swizzled (chunk ^= (row>>1)&3, 16B chunks) via pre-swizzled
// global_load_lds SOURCE (rule 21) + swizzled ds_read — kills the 8-way conflict.
__global__ __launch_bounds__(256) void k_gemm(const u16* __restrict__ A, const u16* __restrict__ B,
                                              float* __restrict__ C, int K, int ldc, int nvalid,
                                              const float* __restrict__ bias) {
  __shared__ u16 As[128 * 32];
  __shared__ u16 Bs[128 * 32];
  const int tid = threadIdx.x, lane = tid & 63, wid = tid >> 6;
  const int wm = wid >> 1, wn = wid & 1;
  const int bm = blockIdx.x, bn = blockIdx.y;
  const int r4 = tid >> 2;
  const int csw = (((tid & 3) ^ ((r4 >> 1) & 3))) * 8;  // pre-swizzled source chunk
  f32x4 acc[4][4] = {};
  const u16* Ab = A + (size_t)bm * 128 * K;
  const u16* Bb = B + (size_t)bn * 128 * K;
  const int nkt = K >> 5;
  for (int kt = 0; kt < nkt; ++kt) {
    const int k0 = kt * 32;
    __syncthreads();  // protect LDS from overwrite
#pragma unroll
    for (int c = 0; c < 2; ++c) {
      gload16(Ab + (size_t)(c * 64 + r4) * K + k0 + csw, &As[c * 2048 + wid * 512]);
      gload16(Bb + (size_t)(c * 64 + r4) * K + k0 + csw, &Bs[c * 2048 + wid * 512]);
    }
    __syncthreads();  // drains vmcnt: LDS tiles ready
    short8 af[4], bf[4];
    const int rr = lane & 15, g = lane >> 4;
    const int kq2 = ((g ^ ((rr >> 1) & 3))) * 8;  // swizzled read chunk
#pragma unroll
    for (int mi = 0; mi < 4; ++mi) af[mi] = *(const short8*)&As[(wm * 64 + mi * 16 + rr) * 32 + kq2];
#pragma unroll
    for (int ni = 0; ni < 4; ++ni) bf[ni] = *(const short8*)&Bs[(wn * 64 + ni * 16 + rr) * 32 + kq2];
#pragma unroll
    for (int mi = 0; mi < 4; ++mi)
#pragma unroll
      for (int ni = 0; ni < 4; ++ni) acc[mi][ni] = mfma_bf16(af[mi], bf[ni], acc[mi][ni]);
  }
#pragma unroll
  for (int mi = 0; mi < 4; ++mi)
#pragma unroll
    for (int ni = 0; ni < 4; ++ni) {
      const int col = bn * 128 + wn * 64 + ni * 16 + (lane & 15);
      if (col < nvalid) {
        const float bb = bias ? bias[col] : 0.0f;
#pragma unroll
        for (int r = 0; r < 4; ++r) {
          const int row = bm * 128 + wm * 64 + mi * 16 + (lane >> 4) * 4 + r;
          C[(size_t)row * ldc + col] = acc[mi][ni][r] + bb;
        }
      }
    }
}

// ---------------- persistent recurrent kernel ----------------
// 128 blocks x 256 threads, cooperative. Blocks 0..63: h1-job, 16-col slab each,
// W1x+W1h slabs in LDS (64KB). Blocks 64..127: h0-job, W0h slab in LDS (32KB).
// Weights staged ONCE (swizzled: 16B chunk ^= row&7), then 129 grid.sync()'d steps.
__device__ __forceinline__ void slab_acc(const u16* __restrict__ A, const u16* __restrict__ Ws,
                                         int wid, int lane, f32x4* acc) {
  const int rr = lane & 15, g = lane >> 4;
  const u16* ap = A + (size_t)(wid * 16 + rr) * HID + g * 8;
  const int sw = rr & 7;
#pragma unroll
  for (int kt = 0; kt < 32; ++kt) {
    short8 af = *(const short8*)(ap + kt * 32);
    short8 bf = *(const short8*)&Ws[rr * HID + (((kt * 4 + g) ^ sw) * 8)];
    *acc = mfma_bf16(af, bf, *acc);
  }
}

__global__ __launch_bounds__(256) void k_rnn(const u16* __restrict__ W0h,
                                             const u16* __restrict__ W1x,
                                             const u16* __restrict__ W1h,
                                             const float* __restrict__ pre0,
                                             const float* __restrict__ b0,
                                             const float* __restrict__ b1, u16* __restrict__ H0all,
                                             u16* __restrict__ H1all, const u16* __restrict__ Zb) {
  cg::grid_group grid = cg::this_grid();
  __shared__ u16 Wl[2][16 * 1024];  // 64KB
  const int bid = blockIdx.x;
  const bool is_h1 = bid < 64;
  const int c0 = (bid & 63) * 16;
  const int tid = threadIdx.x, lane = tid & 63, wid = tid >> 6;

  // stage weight slab(s) to LDS, swizzled (chunk ^= row&7; 16B chunks, row stride 2KB)
  {
    const u16* Wa = is_h1 ? W1x : W0h;
#pragma unroll
    for (int i = 0; i < 8; ++i) {
      int ch = tid + i * 256;  // 0..2047  (chunk id over 16 rows x 128 chunks)
      int row = ch >> 7, c = ch & 127;
      int sc = c ^ (row & 7);
      *(short8*)&Wl[0][row * 1024 + sc * 8] = *(const short8*)&Wa[(size_t)(c0 + row) * HID + c * 8];
      if (is_h1)
        *(short8*)&Wl[1][row * 1024 + sc * 8] =
            *(const short8*)&W1h[(size_t)(c0 + row) * HID + c * 8];
    }
  }
  __syncthreads();

  const float bb = (is_h1 ? b1 : b0)[c0 + (lane & 15)];
  const int col = c0 + (lane & 15);
  const int row0 = wid * 16 + (lane >> 4) * 4;

  // bootstrap: h0[0] = tanh(hidden0 @ W0h^T + pre0[0] + b0)
  if (!is_h1) {
    f32x4 acc = {};
    slab_acc(Zb, &Wl[0][0], wid, lane, &acc);
#pragma unroll
    for (int r = 0; r < 4; ++r)
      H0all[(row0 + r) * HID + col] = f2bf(tanhf(acc[r] + pre0[(row0 + r) * HID + col] + bb));
  }
  grid.sync();

  for (int t = 0; t < SEQ; ++t) {
    if (is_h1) {
      f32x4 acc = {};
      slab_acc(H0all + (size_t)t * BH, &Wl[0][0], wid, lane, &acc);
      const u16* A2 = t ? (H1all + (size_t)(t - 1) * BH) : (Zb + BH);
      slab_acc(A2, &Wl[1][0], wid, lane, &acc);
      u16* out = H1all + (size_t)t * BH;
#pragma unroll
      for (int r = 0; r < 4; ++r) out[(row0 + r) * HID + col] = f2bf(tanhf(acc[r] + bb));
    } else if (t < SEQ - 1) {
      f32x4 acc = {};
      slab_acc(H0all + (size_t)t * BH, &Wl[0][0], wid, lane, &acc);
      const float* ci = pre0 + (size_t)(t + 1) * BH;
      u16* out = H0all + (size_t)(t + 1) * BH;
#pragma unroll
      for (int r = 0; r < 4; ++r)
        out[(row0 + r) * HID + col] = f2bf(tanhf(acc[r] + ci[(row0 + r) * HID + col] + bb));
    }
    grid.sync();
  }
}

__global__ void k_finalh(const u16* __restrict__ H0all, const u16* __restrict__ H1all,
                         float* __restrict__ out) {
  int i = blockIdx.x * 256 + threadIdx.x;
  if (i < 2 * BH) {
    u16 v = (i < BH) ? H0all[(size_t)(SEQ - 1) * BH + i] : H1all[(size_t)(SEQ - 1) * BH + (i - BH)];
    out[(size_t)MROWS * VOCAB + i] = bf2f(v);
  }
}

extern "C" void kernel_launch(void* const* d_in, const int* in_sizes, int n_in, void* d_out,
                              int out_size, void* d_ws, size_t ws_size, hipStream_t stream) {
  (void)in_sizes; (void)n_in; (void)out_size; (void)ws_size;
  const int* toks = (const int*)d_in[0];
  const float* hid0 = (const float*)d_in[1];
  const float* emb = (const float*)d_in[2];
  const float* W0x = (const float*)d_in[3];
  const float* W0h = (const float*)d_in[4];
  const float* b0 = (const float*)d_in[5];
  const float* W1x = (const float*)d_in[6];
  const float* W1h = (const float*)d_in[7];
  const float* b1 = (const float*)d_in[8];
  const float* Wout = (const float*)d_in[9];
  const float* bout = (const float*)d_in[10];
  float* out = (float*)d_out;

  char* ws = (char*)d_ws;
  u16* Xb = (u16*)(ws);                    //  8,388,608 B
  u16* W0xb = (u16*)(ws + 8388608);        //  1,048,576
  u16* W0hb = (u16*)(ws + 9437184);        //  2,097,152
  u16* W1xb = (u16*)(ws + 11534336);       //  2,097,152
  u16* W1hb = (u16*)(ws + 13631488);       //  2,097,152
  u16* Woutb = (u16*)(ws + 15728640);      // 20,971,520
  float* pre0 = (float*)(ws + 36700160);   // 33,554,432
  u16* H0all = (u16*)(ws + 70254592);      // 16,777,216
  u16* H1all = (u16*)(ws + 87031808);      // 16,777,216
  u16* Zb = (u16*)(ws + 103809024);        //    262,144  (total ~99.3 MB)

  auto g = [](int n) { return dim3((unsigned)((n + 255) / 256)); };
  k_cvt<<<g(HID * EMB), 256, 0, stream>>>(W0x, W0xb, HID * EMB);
  k_cvt<<<g(HID * HID), 256, 0, stream>>>(W0h, W0hb, HID * HID);
  k_cvt<<<g(HID * HID), 256, 0, stream>>>(W1x, W1xb, HID * HID);
  k_cvt<<<g(HID * HID), 256, 0, stream>>>(W1h, W1hb, HID * HID);
  k_cvt<<<g(2 * BH), 256, 0, stream>>>(hid0, Zb, 2 * BH);
  k_cvt_wout<<<g(NPAD * HID), 256, 0, stream>>>(Wout, Woutb);
  k_gather<<<g(MROWS * EMB), 256, 0, stream>>>(toks, emb, Xb);

  // pre0[all t] = X @ W0x^T   (8192 x 1024, K=512)
  k_gemm<<<dim3(MROWS / 128, HID / 128), 256, 0, stream>>>(Xb, W0xb, pre0, EMB, HID, HID, nullptr);

  // recurrence: persistent cooperative kernel, one grid.sync per step
  {
    void* args[] = {(void*)&W0hb, (void*)&W1xb, (void*)&W1hb, (void*)&pre0, (void*)&b0,
                    (void*)&b1,   (void*)&H0all, (void*)&H1all, (void*)&Zb};
    hipLaunchCooperativeKernel((const void*)k_rnn, dim3(128), dim3(256), args, 0, stream);
  }

  // logits = H1 @ Wout^T + bout   (8192 x 10240(pad), K=1024)
  k_gemm<<<dim3(MROWS / 128, NPAD / 128), 256, 0, stream>>>(H1all, Woutb, out, HID, VOCAB, VOCAB,
                                                            bout);
  k_finalh<<<g(2 * BH), 256, 0, stream>>>(H0all, H1all, out);
}

// Round 4
// 2394.903 us; speedup vs baseline: 2.4027x; 1.5563x over previous
//
#include <hip/hip_runtime.h>
#include <hip/hip_bf16.h>

#define SEQ 128
#define BATCH 64
#define EMB 512
#define HID 1024
#define VOCAB 10000
#define NPAD 10240
#define MROWS 8192  // SEQ*BATCH
#define BH (BATCH * HID)

typedef unsigned short u16;
typedef unsigned int u32;
typedef __attribute__((ext_vector_type(4))) float f32x4;
typedef __attribute__((ext_vector_type(8))) short short8;
typedef __attribute__((ext_vector_type(8))) __bf16 bf16x8;

__device__ __forceinline__ u16 f2bf(float f) {
  u32 u = __builtin_bit_cast(u32, f);
  u = (u + 0x7fffu + ((u >> 16) & 1u)) >> 16;  // RNE
  return (u16)u;
}
__device__ __forceinline__ float bf2f(u16 h) {
  u32 u = ((u32)h) << 16;
  return __builtin_bit_cast(float, u);
}
__device__ __forceinline__ f32x4 mfma_bf16(short8 a, short8 b, f32x4 c) {
  return __builtin_amdgcn_mfma_f32_16x16x32_bf16(
      __builtin_bit_cast(bf16x8, a), __builtin_bit_cast(bf16x8, b), c, 0, 0, 0);
}
__device__ __forceinline__ void gload16(const u16* g, u16* l) {
  __builtin_amdgcn_global_load_lds(
      (__attribute__((address_space(1))) void*)g,
      (__attribute__((address_space(3))) void*)l, 16, 0, 0);
}

// ---------------- prep kernels ----------------
__global__ void k_cvt(const float* __restrict__ s, u16* __restrict__ d, int n) {
  int i = blockIdx.x * 256 + threadIdx.x;
  if (i < n) d[i] = f2bf(s[i]);
}
__global__ void k_cvt_wout(const float* __restrict__ s, u16* __restrict__ d) {
  int i = blockIdx.x * 256 + threadIdx.x;  // over NPAD*HID
  if (i < NPAD * HID) {
    int row = i >> 10;
    d[i] = (row < VOCAB) ? f2bf(s[i]) : (u16)0;
  }
}
__global__ void k_gather(const int* __restrict__ toks, const float* __restrict__ emb,
                         u16* __restrict__ X) {
  int i = blockIdx.x * 256 + threadIdx.x;  // over MROWS*EMB
  if (i < MROWS * EMB) {
    int r = i >> 9, e = i & 511;
    X[i] = f2bf(emb[(size_t)toks[r] * EMB + e]);
  }
}
__global__ void k_zero(int* __restrict__ p, int n) {
  int i = blockIdx.x * 256 + threadIdx.x;
  if (i < n) p[i] = 0;
}

// ---------------- big GEMM: C[M,N] = A[M,K] @ B[N,K]^T (+bias) ----------------
__global__ __launch_bounds__(256) void k_gemm(const u16* __restrict__ A, const u16* __restrict__ B,
                                              float* __restrict__ C, int K, int ldc, int nvalid,
                                              const float* __restrict__ bias) {
  __shared__ u16 As[128 * 32];
  __shared__ u16 Bs[128 * 32];
  const int tid = threadIdx.x, lane = tid & 63, wid = tid >> 6;
  const int wm = wid >> 1, wn = wid & 1;
  const int bm = blockIdx.x, bn = blockIdx.y;
  const int r4 = tid >> 2;
  const int csw = (((tid & 3) ^ ((r4 >> 1) & 3))) * 8;  // pre-swizzled source chunk
  f32x4 acc[4][4] = {};
  const u16* Ab = A + (size_t)bm * 128 * K;
  const u16* Bb = B + (size_t)bn * 128 * K;
  const int nkt = K >> 5;
  for (int kt = 0; kt < nkt; ++kt) {
    const int k0 = kt * 32;
    __syncthreads();
#pragma unroll
    for (int c = 0; c < 2; ++c) {
      gload16(Ab + (size_t)(c * 64 + r4) * K + k0 + csw, &As[c * 2048 + wid * 512]);
      gload16(Bb + (size_t)(c * 64 + r4) * K + k0 + csw, &Bs[c * 2048 + wid * 512]);
    }
    __syncthreads();
    short8 af[4], bf[4];
    const int rr = lane & 15, g = lane >> 4;
    const int kq2 = ((g ^ ((rr >> 1) & 3))) * 8;  // swizzled read chunk
#pragma unroll
    for (int mi = 0; mi < 4; ++mi) af[mi] = *(const short8*)&As[(wm * 64 + mi * 16 + rr) * 32 + kq2];
#pragma unroll
    for (int ni = 0; ni < 4; ++ni) bf[ni] = *(const short8*)&Bs[(wn * 64 + ni * 16 + rr) * 32 + kq2];
#pragma unroll
    for (int mi = 0; mi < 4; ++mi)
#pragma unroll
      for (int ni = 0; ni < 4; ++ni) acc[mi][ni] = mfma_bf16(af[mi], bf[ni], acc[mi][ni]);
  }
#pragma unroll
  for (int mi = 0; mi < 4; ++mi)
#pragma unroll
    for (int ni = 0; ni < 4; ++ni) {
      const int col = bn * 128 + wn * 64 + ni * 16 + (lane & 15);
      if (col < nvalid) {
        const float bb = bias ? bias[col] : 0.0f;
#pragma unroll
        for (int r = 0; r < 4; ++r) {
          const int row = bm * 128 + wm * 64 + mi * 16 + (lane >> 4) * 4 + r;
          C[(size_t)row * ldc + col] = acc[mi][ni][r] + bb;
        }
      }
    }
}

// ---------------- fast hierarchical grid barrier ----------------
// bar layout (ints): grp[16] counters at stride 64; rootc at [1024]; gen at [1088].
// Monotone counters, no resets. Relaxed agent atomics (IC-coherent) for the
// protocol; one __threadfence() pair per block per step for data rel/acq.
__device__ __forceinline__ void gbar(int* bar, int bid, int step) {
  __syncthreads();  // all block threads' stores issued+drained (compiler waits vmcnt)
  if (threadIdx.x == 0) {
    __threadfence();  // release: L2 writeback so other XCDs see our H writes
    int a = atomicAdd(&bar[(bid >> 3) * 64], 1);
    if (a == (step + 1) * 8 - 1) {
      int r = atomicAdd(&bar[1024], 1);
      if (r == (step + 1) * 16 - 1)
        __hip_atomic_store(&bar[1088], step + 1, __ATOMIC_RELAXED, __HIP_MEMORY_SCOPE_AGENT);
    }
    while (__hip_atomic_load(&bar[1088], __ATOMIC_RELAXED, __HIP_MEMORY_SCOPE_AGENT) < step + 1)
      __builtin_amdgcn_s_sleep(1);
    __threadfence();  // acquire: invalidate so we read fresh H data
  }
  __syncthreads();
}

// ---------------- persistent recurrent kernel ----------------
// 128 blocks x 512 threads. Blocks 0..63: h1-job (16-col slab; waves 0-3 do
// H0[t]@W1x^T, waves 4-7 do H1[t-1]@W1h^T, merge via LDS). Blocks 64..127:
// h0-job (waves split K 512/512). Weights staged once, swizzled.
template <int NKT>
__device__ __forceinline__ void slab_acc(const u16* __restrict__ A, const u16* __restrict__ Ws,
                                         int kt0, int rowbase, int lane, f32x4* acc) {
  const int rr = lane & 15, g = lane >> 4;
  const u16* ap = A + (size_t)(rowbase + rr) * HID + g * 8;
  const int sw = rr & 7;
#pragma unroll
  for (int i = 0; i < NKT; ++i) {
    const int kt = kt0 + i;
    short8 af = *(const short8*)(ap + kt * 32);
    short8 bf = *(const short8*)&Ws[rr * 1024 + (((kt * 4 + g) ^ sw) * 8)];
    *acc = mfma_bf16(af, bf, *acc);
  }
}

__global__ __launch_bounds__(512) void k_rnn(const u16* __restrict__ W0h,
                                             const u16* __restrict__ W1x,
                                             const u16* __restrict__ W1h,
                                             const float* __restrict__ pre0,
                                             const float* __restrict__ b0,
                                             const float* __restrict__ b1, u16* __restrict__ H0all,
                                             u16* __restrict__ H1all, const u16* __restrict__ Zb,
                                             int* __restrict__ bar) {
  __shared__ u16 Wl[2][16 * 1024];  // 64KB
  __shared__ float Pf[64][20];      // padded partial buffer (5KB)
  const int bid = blockIdx.x;
  const bool is_h1 = bid < 64;
  const int c0 = (bid & 63) * 16;
  const int tid = threadIdx.x, lane = tid & 63, wid = tid >> 6;
  const int rr = lane & 15, g = lane >> 4;
  const int rowbase = (wid & 3) * 16;

  // stage weight slab(s) to LDS, swizzled (16B chunk ^= row&7)
  {
    const u16* Wa = is_h1 ? W1x : W0h;
#pragma unroll
    for (int i = 0; i < 4; ++i) {
      int ch = tid + i * 512, row = ch >> 7, c = ch & 127, sc = c ^ (row & 7);
      *(short8*)&Wl[0][row * 1024 + sc * 8] = *(const short8*)&Wa[(size_t)(c0 + row) * HID + c * 8];
      if (is_h1)
        *(short8*)&Wl[1][row * 1024 + sc * 8] =
            *(const short8*)&W1h[(size_t)(c0 + row) * HID + c * 8];
    }
  }
  __syncthreads();

  const float bb = (is_h1 ? b1 : b0)[c0 + rr];
  const int col = c0 + rr;
  const int orow = rowbase + g * 4;

  // bootstrap: h0 blocks compute H0[0] = tanh(hid0@W0h^T + pre0[0] + b0)
  {
    f32x4 acc = {};
    if (!is_h1) {
      slab_acc<16>(Zb, &Wl[0][0], (wid < 4) ? 0 : 16, rowbase, lane, &acc);
      if (wid >= 4)
#pragma unroll
        for (int r = 0; r < 4; ++r) Pf[orow + r][rr] = acc[r];
    }
    __syncthreads();
    if (!is_h1 && wid < 4)
#pragma unroll
      for (int r = 0; r < 4; ++r)
        H0all[(orow + r) * HID + col] =
            f2bf(tanhf(acc[r] + Pf[orow + r][rr] + pre0[(orow + r) * HID + col] + bb));
  }
  gbar(bar, bid, 0);

  for (int t = 0; t < SEQ; ++t) {
    if (is_h1) {
      f32x4 acc = {};
      if (wid < 4) {
        slab_acc<32>(H0all + (size_t)t * BH, &Wl[0][0], 0, rowbase, lane, &acc);
      } else {
        const u16* A2 = t ? (H1all + (size_t)(t - 1) * BH) : (Zb + BH);
        slab_acc<32>(A2, &Wl[1][0], 0, rowbase, lane, &acc);
#pragma unroll
        for (int r = 0; r < 4; ++r) Pf[orow + r][rr] = acc[r];
      }
      __syncthreads();
      if (wid < 4) {
        u16* out = H1all + (size_t)t * BH;
#pragma unroll
        for (int r = 0; r < 4; ++r)
          out[(orow + r) * HID + col] = f2bf(tanhf(acc[r] + Pf[orow + r][rr] + bb));
      }
    } else {
      f32x4 acc = {};
      const bool live = t < SEQ - 1;
      if (live) {
        slab_acc<16>(H0all + (size_t)t * BH, &Wl[0][0], (wid < 4) ? 0 : 16, rowbase, lane, &acc);
        if (wid >= 4)
#pragma unroll
          for (int r = 0; r < 4; ++r) Pf[orow + r][rr] = acc[r];
      }
      __syncthreads();
      if (live && wid < 4) {
        const float* ci = pre0 + (size_t)(t + 1) * BH;
        u16* out = H0all + (size_t)(t + 1) * BH;
#pragma unroll
        for (int r = 0; r < 4; ++r)
          out[(orow + r) * HID + col] =
              f2bf(tanhf(acc[r] + Pf[orow + r][rr] + ci[(orow + r) * HID + col] + bb));
      }
    }
    gbar(bar, bid, t + 1);
  }
}

__global__ void k_finalh(const u16* __restrict__ H0all, const u16* __restrict__ H1all,
                         float* __restrict__ out) {
  int i = blockIdx.x * 256 + threadIdx.x;
  if (i < 2 * BH) {
    u16 v = (i < BH) ? H0all[(size_t)(SEQ - 1) * BH + i] : H1all[(size_t)(SEQ - 1) * BH + (i - BH)];
    out[(size_t)MROWS * VOCAB + i] = bf2f(v);
  }
}

extern "C" void kernel_launch(void* const* d_in, const int* in_sizes, int n_in, void* d_out,
                              int out_size, void* d_ws, size_t ws_size, hipStream_t stream) {
  (void)in_sizes; (void)n_in; (void)out_size; (void)ws_size;
  const int* toks = (const int*)d_in[0];
  const float* hid0 = (const float*)d_in[1];
  const float* emb = (const float*)d_in[2];
  const float* W0x = (const float*)d_in[3];
  const float* W0h = (const float*)d_in[4];
  const float* b0 = (const float*)d_in[5];
  const float* W1x = (const float*)d_in[6];
  const float* W1h = (const float*)d_in[7];
  const float* b1 = (const float*)d_in[8];
  const float* Wout = (const float*)d_in[9];
  const float* bout = (const float*)d_in[10];
  float* out = (float*)d_out;

  char* ws = (char*)d_ws;
  u16* Xb = (u16*)(ws);                    //  8,388,608 B
  u16* W0xb = (u16*)(ws + 8388608);        //  1,048,576
  u16* W0hb = (u16*)(ws + 9437184);        //  2,097,152
  u16* W1xb = (u16*)(ws + 11534336);       //  2,097,152
  u16* W1hb = (u16*)(ws + 13631488);       //  2,097,152
  u16* Woutb = (u16*)(ws + 15728640);      // 20,971,520
  float* pre0 = (float*)(ws + 36700160);   // 33,554,432
  u16* H0all = (u16*)(ws + 70254592);      // 16,777,216
  u16* H1all = (u16*)(ws + 87031808);      // 16,777,216
  u16* Zb = (u16*)(ws + 103809024);        //    262,144
  int* bar = (int*)(ws + 104071168);       //      4,608  (total ~99.3 MB)

  auto g = [](int n) { return dim3((unsigned)((n + 255) / 256)); };
  k_zero<<<g(1152), 256, 0, stream>>>(bar, 1152);
  k_cvt<<<g(HID * EMB), 256, 0, stream>>>(W0x, W0xb, HID * EMB);
  k_cvt<<<g(HID * HID), 256, 0, stream>>>(W0h, W0hb, HID * HID);
  k_cvt<<<g(HID * HID), 256, 0, stream>>>(W1x, W1xb, HID * HID);
  k_cvt<<<g(HID * HID), 256, 0, stream>>>(W1h, W1hb, HID * HID);
  k_cvt<<<g(2 * BH), 256, 0, stream>>>(hid0, Zb, 2 * BH);
  k_cvt_wout<<<g(NPAD * HID), 256, 0, stream>>>(Wout, Woutb);
  k_gather<<<g(MROWS * EMB), 256, 0, stream>>>(toks, emb, Xb);

  // pre0[all t] = X @ W0x^T   (8192 x 1024, K=512)
  k_gemm<<<dim3(MROWS / 128, HID / 128), 256, 0, stream>>>(Xb, W0xb, pre0, EMB, HID, HID, nullptr);

  // recurrence: persistent cooperative kernel, custom barrier per step
  {
    void* args[] = {(void*)&W0hb, (void*)&W1xb, (void*)&W1hb, (void*)&pre0, (void*)&b0,
                    (void*)&b1,   (void*)&H0all, (void*)&H1all, (void*)&Zb, (void*)&bar};
    hipLaunchCooperativeKernel((const void*)k_rnn, dim3(128), dim3(512), args, 0, stream);
  }

  // logits = H1 @ Wout^T + bout   (8192 x 10240(pad), K=1024)
  k_gemm<<<dim3(MROWS / 128, NPAD / 128), 256, 0, stream>>>(H1all, Woutb, out, HID, VOCAB, VOCAB,
                                                            bout);
  k_finalh<<<g(2 * BH), 256, 0, stream>>>(H0all, H1all, out);
}

// Round 5
// 2026.702 us; speedup vs baseline: 2.8392x; 1.1817x over previous
//
#include <hip/hip_runtime.h>
#include <hip/hip_bf16.h>

#define SEQ 128
#define BATCH 64
#define EMB 512
#define HID 1024
#define VOCAB 10000
#define NPAD 10240
#define MROWS 8192  // SEQ*BATCH
#define BH (BATCH * HID)

typedef unsigned short u16;
typedef unsigned int u32;
typedef __attribute__((ext_vector_type(4))) float f32x4;
typedef __attribute__((ext_vector_type(8))) short short8;
typedef __attribute__((ext_vector_type(8))) __bf16 bf16x8;

__device__ __forceinline__ u16 f2bf(float f) {
  u32 u = __builtin_bit_cast(u32, f);
  u = (u + 0x7fffu + ((u >> 16) & 1u)) >> 16;  // RNE
  return (u16)u;
}
__device__ __forceinline__ float bf2f(u16 h) {
  u32 u = ((u32)h) << 16;
  return __builtin_bit_cast(float, u);
}
__device__ __forceinline__ f32x4 mfma_bf16(short8 a, short8 b, f32x4 c) {
  return __builtin_amdgcn_mfma_f32_16x16x32_bf16(
      __builtin_bit_cast(bf16x8, a), __builtin_bit_cast(bf16x8, b), c, 0, 0, 0);
}
__device__ __forceinline__ void gload16(const u16* g, u16* l) {
  __builtin_amdgcn_global_load_lds(
      (__attribute__((address_space(1))) void*)g,
      (__attribute__((address_space(3))) void*)l, 16, 0, 0);
}
// write-through store to IC (coherence point) — makes cross-XCD handoff fence-free
__device__ __forceinline__ void st_ic(u16* p, u16 v) {
  asm volatile("global_store_short %0, %1, off sc0 sc1" ::"v"(p), "v"((u32)v) : "memory");
}

// ---------------- prep kernels ----------------
__global__ void k_cvt(const float* __restrict__ s, u16* __restrict__ d, int n) {
  int i = blockIdx.x * 256 + threadIdx.x;
  if (i < n) d[i] = f2bf(s[i]);
}
__global__ void k_cvt_wout(const float* __restrict__ s, u16* __restrict__ d) {
  int i = blockIdx.x * 256 + threadIdx.x;  // over NPAD*HID
  if (i < NPAD * HID) {
    int row = i >> 10;
    d[i] = (row < VOCAB) ? f2bf(s[i]) : (u16)0;
  }
}
__global__ void k_gather(const int* __restrict__ toks, const float* __restrict__ emb,
                         u16* __restrict__ X) {
  int i = blockIdx.x * 256 + threadIdx.x;  // over MROWS*EMB
  if (i < MROWS * EMB) {
    int r = i >> 9, e = i & 511;
    X[i] = f2bf(emb[(size_t)toks[r] * EMB + e]);
  }
}
__global__ void k_zero(int* __restrict__ p, int n) {
  int i = blockIdx.x * 256 + threadIdx.x;
  if (i < n) p[i] = 0;
}

// ---------------- big GEMM: C[M,N] = A[M,K] @ B[N,K]^T (+bias) ----------------
__global__ __launch_bounds__(256) void k_gemm(const u16* __restrict__ A, const u16* __restrict__ B,
                                              float* __restrict__ C, int K, int ldc, int nvalid,
                                              const float* __restrict__ bias) {
  __shared__ u16 As[128 * 32];
  __shared__ u16 Bs[128 * 32];
  const int tid = threadIdx.x, lane = tid & 63, wid = tid >> 6;
  const int wm = wid >> 1, wn = wid & 1;
  const int bm = blockIdx.x, bn = blockIdx.y;
  const int r4 = tid >> 2;
  const int csw = (((tid & 3) ^ ((r4 >> 1) & 3))) * 8;  // pre-swizzled source chunk
  f32x4 acc[4][4] = {};
  const u16* Ab = A + (size_t)bm * 128 * K;
  const u16* Bb = B + (size_t)bn * 128 * K;
  const int nkt = K >> 5;
  for (int kt = 0; kt < nkt; ++kt) {
    const int k0 = kt * 32;
    __syncthreads();
#pragma unroll
    for (int c = 0; c < 2; ++c) {
      gload16(Ab + (size_t)(c * 64 + r4) * K + k0 + csw, &As[c * 2048 + wid * 512]);
      gload16(Bb + (size_t)(c * 64 + r4) * K + k0 + csw, &Bs[c * 2048 + wid * 512]);
    }
    __syncthreads();
    short8 af[4], bf[4];
    const int rr = lane & 15, g = lane >> 4;
    const int kq2 = ((g ^ ((rr >> 1) & 3))) * 8;  // swizzled read chunk
#pragma unroll
    for (int mi = 0; mi < 4; ++mi) af[mi] = *(const short8*)&As[(wm * 64 + mi * 16 + rr) * 32 + kq2];
#pragma unroll
    for (int ni = 0; ni < 4; ++ni) bf[ni] = *(const short8*)&Bs[(wn * 64 + ni * 16 + rr) * 32 + kq2];
#pragma unroll
    for (int mi = 0; mi < 4; ++mi)
#pragma unroll
      for (int ni = 0; ni < 4; ++ni) acc[mi][ni] = mfma_bf16(af[mi], bf[ni], acc[mi][ni]);
  }
#pragma unroll
  for (int mi = 0; mi < 4; ++mi)
#pragma unroll
    for (int ni = 0; ni < 4; ++ni) {
      const int col = bn * 128 + wn * 64 + ni * 16 + (lane & 15);
      if (col < nvalid) {
        const float bb = bias ? bias[col] : 0.0f;
#pragma unroll
        for (int r = 0; r < 4; ++r) {
          const int row = bm * 128 + wm * 64 + mi * 16 + (lane >> 4) * 4 + r;
          C[(size_t)row * ldc + col] = acc[mi][ni][r] + bb;
        }
      }
    }
}

// ---------------- fast hierarchical grid barrier (fence-free) ----------------
// bar: grp[16] counters at int-stride 64; root at [1024]. Monotone, no resets.
// Data visibility comes from write-through (sc0 sc1) H stores drained by the
// explicit vmcnt(0) below — no cache writeback/invalidate instructions at all.
__device__ __forceinline__ void gbar(int* bar, int bid, int step) {
  asm volatile("s_waitcnt vmcnt(0)" ::: "memory");  // per-wave: drain asm sc-stores
  __syncthreads();
  if (threadIdx.x == 0) {
    int a = atomicAdd(&bar[(bid >> 3) * 64], 1);  // agent-scope, IC-resident
    if (a == (step + 1) * 8 - 1) atomicAdd(&bar[1024], 1);
    const int tgt = (step + 1) * 16;
    while (__hip_atomic_load(&bar[1024], __ATOMIC_RELAXED, __HIP_MEMORY_SCOPE_AGENT) < tgt)
      __builtin_amdgcn_s_sleep(2);
  }
  __syncthreads();
}

// ---------------- persistent recurrent kernel ----------------
// 128 blocks x 512 threads. Blocks 0..63: h1-job (16-col slab; waves 0-3 do
// H0[t]@W1x^T, waves 4-7 do H1[t-1]@W1h^T, merge via LDS). Blocks 64..127:
// h0-job (waves split K 512/512). Weights staged once in LDS, swizzled.
// slab_acc: two-phase (issue ALL A-loads, then MFMA-consume) so the compiler
// keeps the full load stream in flight (~NKT*8 VGPRs) — hides IC latency.
template <int NKT>
__device__ __forceinline__ void slab_acc(const u16* __restrict__ A, const u16* __restrict__ Ws,
                                         int kt0, int rowbase, int lane, f32x4* acc) {
  const int rr = lane & 15, g = lane >> 4;
  const u16* ap = A + (size_t)(rowbase + rr) * HID + g * 8;
  const int sw = rr & 7;
  short8 af[NKT];
#pragma unroll
  for (int i = 0; i < NKT; ++i) af[i] = *(const short8*)(ap + (size_t)(kt0 + i) * 32);
#pragma unroll
  for (int i = 0; i < NKT; ++i) {
    const int kt = kt0 + i;
    short8 bf = *(const short8*)&Ws[rr * 1024 + (((kt * 4 + g) ^ sw) * 8)];
    *acc = mfma_bf16(af[i], bf, *acc);
  }
}

__global__ __launch_bounds__(512) void k_rnn(const u16* __restrict__ W0h,
                                             const u16* __restrict__ W1x,
                                             const u16* __restrict__ W1h,
                                             const float* __restrict__ pre0,
                                             const float* __restrict__ b0,
                                             const float* __restrict__ b1, u16* __restrict__ H0all,
                                             u16* __restrict__ H1all, const u16* __restrict__ Zb,
                                             int* __restrict__ bar) {
  __shared__ u16 Wl[2][16 * 1024];  // 64KB
  __shared__ float Pf[64][20];      // padded partial buffer (5KB)
  const int bid = blockIdx.x;
  const bool is_h1 = bid < 64;
  const int c0 = (bid & 63) * 16;
  const int tid = threadIdx.x, lane = tid & 63, wid = tid >> 6;
  const int rr = lane & 15, g = lane >> 4;
  const int rowbase = (wid & 3) * 16;

  // stage weight slab(s) to LDS, swizzled (16B chunk ^= row&7)
  {
    const u16* Wa = is_h1 ? W1x : W0h;
#pragma unroll
    for (int i = 0; i < 4; ++i) {
      int ch = tid + i * 512, row = ch >> 7, c = ch & 127, sc = c ^ (row & 7);
      *(short8*)&Wl[0][row * 1024 + sc * 8] = *(const short8*)&Wa[(size_t)(c0 + row) * HID + c * 8];
      if (is_h1)
        *(short8*)&Wl[1][row * 1024 + sc * 8] =
            *(const short8*)&W1h[(size_t)(c0 + row) * HID + c * 8];
    }
  }
  __syncthreads();

  const float bb = (is_h1 ? b1 : b0)[c0 + rr];
  const int col = c0 + rr;
  const int orow = rowbase + g * 4;

  // bootstrap: h0 blocks compute H0[0] = tanh(hid0@W0h^T + pre0[0] + b0)
  {
    f32x4 acc = {};
    if (!is_h1) {
      float civ[4];
#pragma unroll
      for (int r = 0; r < 4; ++r) civ[r] = pre0[(orow + r) * HID + col];
      slab_acc<16>(Zb, &Wl[0][0], (wid < 4) ? 0 : 16, rowbase, lane, &acc);
      if (wid >= 4)
#pragma unroll
        for (int r = 0; r < 4; ++r) Pf[orow + r][rr] = acc[r];
      __syncthreads();
      if (wid < 4)
#pragma unroll
        for (int r = 0; r < 4; ++r)
          st_ic(&H0all[(orow + r) * HID + col], f2bf(tanhf(acc[r] + Pf[orow + r][rr] + civ[r] + bb)));
    } else {
      __syncthreads();  // keep barrier counts uniform within block
    }
  }
  gbar(bar, bid, 0);

  for (int t = 0; t < SEQ; ++t) {
    if (is_h1) {
      f32x4 acc = {};
      if (wid < 4) {
        slab_acc<32>(H0all + (size_t)t * BH, &Wl[0][0], 0, rowbase, lane, &acc);
      } else {
        const u16* A2 = t ? (H1all + (size_t)(t - 1) * BH) : (Zb + BH);
        slab_acc<32>(A2, &Wl[1][0], 0, rowbase, lane, &acc);
#pragma unroll
        for (int r = 0; r < 4; ++r) Pf[orow + r][rr] = acc[r];
      }
      __syncthreads();
      if (wid < 4) {
        u16* out = H1all + (size_t)t * BH;
#pragma unroll
        for (int r = 0; r < 4; ++r)
          st_ic(&out[(orow + r) * HID + col], f2bf(tanhf(acc[r] + Pf[orow + r][rr] + bb)));
      }
    } else {
      f32x4 acc = {};
      const bool live = t < SEQ - 1;
      float civ[4];
      if (live) {
        const float* ci = pre0 + (size_t)(t + 1) * BH;
#pragma unroll
        for (int r = 0; r < 4; ++r) civ[r] = ci[(orow + r) * HID + col];
        slab_acc<16>(H0all + (size_t)t * BH, &Wl[0][0], (wid < 4) ? 0 : 16, rowbase, lane, &acc);
        if (wid >= 4)
#pragma unroll
          for (int r = 0; r < 4; ++r) Pf[orow + r][rr] = acc[r];
      }
      __syncthreads();
      if (live && wid < 4) {
        u16* out = H0all + (size_t)(t + 1) * BH;
#pragma unroll
        for (int r = 0; r < 4; ++r)
          st_ic(&out[(orow + r) * HID + col], f2bf(tanhf(acc[r] + Pf[orow + r][rr] + civ[r] + bb)));
      }
    }
    gbar(bar, bid, t + 1);
  }
}

__global__ void k_finalh(const u16* __restrict__ H0all, const u16* __restrict__ H1all,
                         float* __restrict__ out) {
  int i = blockIdx.x * 256 + threadIdx.x;
  if (i < 2 * BH) {
    u16 v = (i < BH) ? H0all[(size_t)(SEQ - 1) * BH + i] : H1all[(size_t)(SEQ - 1) * BH + (i - BH)];
    out[(size_t)MROWS * VOCAB + i] = bf2f(v);
  }
}

extern "C" void kernel_launch(void* const* d_in, const int* in_sizes, int n_in, void* d_out,
                              int out_size, void* d_ws, size_t ws_size, hipStream_t stream) {
  (void)in_sizes; (void)n_in; (void)out_size; (void)ws_size;
  const int* toks = (const int*)d_in[0];
  const float* hid0 = (const float*)d_in[1];
  const float* emb = (const float*)d_in[2];
  const float* W0x = (const float*)d_in[3];
  const float* W0h = (const float*)d_in[4];
  const float* b0 = (const float*)d_in[5];
  const float* W1x = (const float*)d_in[6];
  const float* W1h = (const float*)d_in[7];
  const float* b1 = (const float*)d_in[8];
  const float* Wout = (const float*)d_in[9];
  const float* bout = (const float*)d_in[10];
  float* out = (float*)d_out;

  char* ws = (char*)d_ws;
  u16* Xb = (u16*)(ws);                    //  8,388,608 B
  u16* W0xb = (u16*)(ws + 8388608);        //  1,048,576
  u16* W0hb = (u16*)(ws + 9437184);        //  2,097,152
  u16* W1xb = (u16*)(ws + 11534336);       //  2,097,152
  u16* W1hb = (u16*)(ws + 13631488);       //  2,097,152
  u16* Woutb = (u16*)(ws + 15728640);      // 20,971,520
  float* pre0 = (float*)(ws + 36700160);   // 33,554,432
  u16* H0all = (u16*)(ws + 70254592);      // 16,777,216
  u16* H1all = (u16*)(ws + 87031808);      // 16,777,216
  u16* Zb = (u16*)(ws + 103809024);        //    262,144
  int* bar = (int*)(ws + 104071168);       //      4,608  (total ~99.3 MB)

  auto g = [](int n) { return dim3((unsigned)((n + 255) / 256)); };
  k_zero<<<g(1152), 256, 0, stream>>>(bar, 1152);
  k_cvt<<<g(HID * EMB), 256, 0, stream>>>(W0x, W0xb, HID * EMB);
  k_cvt<<<g(HID * HID), 256, 0, stream>>>(W0h, W0hb, HID * HID);
  k_cvt<<<g(HID * HID), 256, 0, stream>>>(W1x, W1xb, HID * HID);
  k_cvt<<<g(HID * HID), 256, 0, stream>>>(W1h, W1hb, HID * HID);
  k_cvt<<<g(2 * BH), 256, 0, stream>>>(hid0, Zb, 2 * BH);
  k_cvt_wout<<<g(NPAD * HID), 256, 0, stream>>>(Wout, Woutb);
  k_gather<<<g(MROWS * EMB), 256, 0, stream>>>(toks, emb, Xb);

  // pre0[all t] = X @ W0x^T   (8192 x 1024, K=512)
  k_gemm<<<dim3(MROWS / 128, HID / 128), 256, 0, stream>>>(Xb, W0xb, pre0, EMB, HID, HID, nullptr);

  // recurrence: persistent cooperative kernel, fence-free custom barrier per step
  {
    void* args[] = {(void*)&W0hb, (void*)&W1xb, (void*)&W1hb, (void*)&pre0, (void*)&b0,
                    (void*)&b1,   (void*)&H0all, (void*)&H1all, (void*)&Zb, (void*)&bar};
    hipLaunchCooperativeKernel((const void*)k_rnn, dim3(128), dim3(512), args, 0, stream);
  }

  // logits = H1 @ Wout^T + bout   (8192 x 10240(pad), K=1024)
  k_gemm<<<dim3(MROWS / 128, NPAD / 128), 256, 0, stream>>>(H1all, Woutb, out, HID, VOCAB, VOCAB,
                                                            bout);
  k_finalh<<<g(2 * BH), 256, 0, stream>>>(H0all, H1all, out);
}